// Round 30
// baseline (35.653 us; speedup 1.0000x reference)
//
#include <hip/hip_runtime.h>

#define LEN_EPISODE 2048
#define TW 6.283185307179586
#define HH 0.16

// R30: 2 blocks/CU timeline split -- tests per-CU write-stream MLP.
// R25-R29 plateau (27.5-28.6) across producer speed x3, emitters 6/7,
// segments 128/256B => binder is effective write BW (~4.9 TB/s vs memset
// 6.5). Last untested lever: number of concurrent writer waves per CU.
// 512 blocks; pair (grp, grp+256) shares 64 pendulums: half=0 owns steps
// 0-63, half=1 owns 64-127 (producer runs a redundant non-publishing
// 64-step prefix -- same STEPP chain, bit-identical trajectory).
// Per block: 6 waves = producer + 5 pair-emitters; LDS 75KB -> 2 blocks/CU.
// Emit machinery identical to R28 (pairs, 128B-line flushes) => absmax 0.875.

#define STEPP() do {                                                        \
    const float f1 = Atil * rcf;                                            \
    const float f2 = __builtin_fmaf(nA2s, rsf, A2c * rcf);                  \
    const float f3 = __builtin_fmaf(nA3s, rsf, A3c * rcf);                  \
    rcn = __builtin_fmaf(nsdf, rsf, rcf * cdf);                             \
    rsn = __builtin_fmaf(sdf, rcf, rsf * cdf);                              \
    const float f4 = Atil * rcn;                                            \
    const float s1  = __builtin_amdgcn_sinf(U);                             \
    const float U2  = __builtin_fmaf(c13, V, U);                            \
    const float s2  = __builtin_amdgcn_sinf(U2);                            \
    const float Ub3 = __builtin_fmaf(c23, V, U);                            \
    const float s3a = __builtin_amdgcn_sinf(Ub3);                           \
    const float c3a = __builtin_amdgcn_cosf(Ub3);                           \
    const float Ub4 = __builtin_fmaf(hh, V, U);                             \
    const float s4a = __builtin_amdgcn_sinf(Ub4);                           \
    const float c4a = __builtin_amdgcn_cosf(Ub4);                           \
    const float k1w = __builtin_fmaf(nw2t, s1, __builtin_fmaf(ngam, V, f1)); \
    const float V2  = __builtin_fmaf(c13, k1w, V);                          \
    const float k2w = __builtin_fmaf(nw2t, s2, __builtin_fmaf(ngam, V2, f2)); \
    const float e3  = tph23 * k1w;                                          \
    const float s3  = __builtin_fmaf(e3, c3a,                               \
                      __builtin_fmaf(-0.5f * e3 * e3, s3a, s3a));           \
    const float V3  = __builtin_fmaf(hh, k2w, __builtin_fmaf(nc13, k1w, V)); \
    const float k3w = __builtin_fmaf(nw2t, s3, __builtin_fmaf(ngam, V3, f3)); \
    const float e4  = __builtin_fmaf(tph2, k2w, n23tph2 * k1w);             \
    const float s4  = __builtin_fmaf(e4, c4a,                               \
                      __builtin_fmaf(-0.5f * e4 * e4, s4a, s4a));           \
    const float V4  = __builtin_fmaf(hh, (k1w - k2w) + k3w, V);             \
    const float k4w = __builtin_fmaf(nw2t, s4, __builtin_fmaf(ngam, V4, f4)); \
    Un = __builtin_fmaf(h8, __builtin_fmaf(3.0f, V2 + V3, V) + V4, U);      \
    Vn = __builtin_fmaf(h8, __builtin_fmaf(3.0f, k2w + k3w, k1w) + k4w, V); \
} while (0)

// Cubic Hermite basis (compile-time doubles), radians+h folded in.
#define B00(t) ((1.0-(t))*(1.0-(t))*(1.0+2.0*(t)))
#define B10(t) ((t)*(1.0-(t))*(1.0-(t)))
#define B01(t) ((t)*(t)*(3.0-2.0*(t)))
#define B11(t) ((t)*(t)*((t)-1.0))
#define HERMT(t)                                                              \
    __builtin_fmaf((float)(TW * B00(t)), U,                                   \
    __builtin_fmaf((float)(TW * B10(t) * HH), V,                              \
    __builtin_fmaf((float)(TW * B01(t)), Un, (float)(TW * B11(t) * HH) * Vn)))

#define EMIT15(dst) do {                                                      \
    (dst)[0]  = HERMT( 1.0/16.0); (dst)[1]  = HERMT( 2.0/16.0);               \
    (dst)[2]  = HERMT( 3.0/16.0); (dst)[3]  = HERMT( 4.0/16.0);               \
    (dst)[4]  = HERMT( 5.0/16.0); (dst)[5]  = HERMT( 6.0/16.0);               \
    (dst)[6]  = HERMT( 7.0/16.0); (dst)[7]  = HERMT( 8.0/16.0);               \
    (dst)[8]  = HERMT( 9.0/16.0); (dst)[9]  = HERMT(10.0/16.0);               \
    (dst)[10] = HERMT(11.0/16.0); (dst)[11] = HERMT(12.0/16.0);               \
    (dst)[12] = HERMT(13.0/16.0); (dst)[13] = HERMT(14.0/16.0);               \
    (dst)[14] = HERMT(15.0/16.0);                                             \
} while (0)

#define COMMIT() do { U = Un; V = Vn; rcf = rcn; rsf = rsn; } while (0)

__global__ __launch_bounds__(384) void pend_kernel(
    const float* __restrict__ init,    // (B, 2)
    const float* __restrict__ params,  // (B, 4)
    float* __restrict__ out,           // (B, LEN_EPISODE)
    int B)
{
    __shared__ float2 ring[65][64];    // [local state 0..64][lane]
    __shared__ float  stag[5][32 * 65];// per-emitter transpose staging (pairs)
    __shared__ int    cnt;             // number of published local states

    const int tid  = threadIdx.x;
    const int lane = tid & 63;
    const int wv   = tid >> 6;          // 0 = producer; 1..5 = emitters
    const int grp  = blockIdx.x & 255;  // pendulum group
    const int half = blockIdx.x >> 8;   // 0: steps 0-63, 1: steps 64-127
    const int b = grp * 64 + lane;

    const float twopi  = 6.283185307179586f;
    const float inv2pi = 0.15915494309189535f;

    const float2 ic = *reinterpret_cast<const float2*>(init + 2 * b);

    if (tid == 0) cnt = 0;
    __syncthreads();                    // cnt initialized before anyone spins

    if (wv == 0) {
        // ---------------- producer: pure integration ----------------
        const float4 p  = *reinterpret_cast<const float4*>(params + 4 * b);
        const float omega = p.x, gamma = p.y, A = p.z, phi = p.w;

        float U = ic.x * inv2pi;
        float V = ic.y * inv2pi;

        const float hh    = 0.16f;
        const float c13   = (float)(0.16 / 3.0);
        const float c23   = (float)(0.32 / 3.0);
        const float nc13  = -c13;
        const float h8    = 0.02f;
        const float tph23 = (float)(TW * 0.16 * 0.16 / 3.0);
        const float tph2  = (float)(TW * 0.16 * 0.16);
        const float n23tph2 = (float)(-TW * 2.0 * 0.16 * 0.16 / 3.0);
        const float ngam  = -gamma;
        const float nw2t  = -(omega * omega) * inv2pi;
        const float Atil  = A * omega * omega * inv2pi;

        const double c_d = 6.283185307179586476925287 * (double)phi;
        const float cdf  = (float)::cos(c_d * 0.16);
        const float sdf  = (float)::sin(c_d * 0.16);
        const float nsdf = -sdf;
        const float A2c  = Atil * (float)::cos(c_d * (0.16 / 3.0));
        const float nA2s = -Atil * (float)::sin(c_d * (0.16 / 3.0));
        const float A3c  = Atil * (float)::cos(c_d * (0.32 / 3.0));
        const float nA3s = -Atil * (float)::sin(c_d * (0.32 / 3.0));

        float rcf = 1.0f, rsf = 0.0f;
        float Un, Vn, rcn, rsn;

        // redundant prefix for the second-half block (no publishing)
        if (half == 1) {
#pragma unroll 4
            for (int k = 0; k < 64; ++k) { STEPP(); COMMIT(); }
        }

        for (int k4 = 0; k4 < 64; k4 += 4) {
#pragma unroll
            for (int j = 0; j < 4; ++j) {
                ring[k4 + j][lane] = make_float2(U, V);
                STEPP(); COMMIT();
            }
            // RELEASE orders the 4 ring writes above.
            if (lane == 0)
                __hip_atomic_store(&cnt, k4 + 4, __ATOMIC_RELEASE,
                                   __HIP_MEMORY_SCOPE_WORKGROUP);
        }
        ring[64][lane] = make_float2(U, V);             // window-final state
        if (lane == 0)
            __hip_atomic_store(&cnt, 65, __ATOMIC_RELEASE,
                               __HIP_MEMORY_SCOPE_WORKGROUP);
    } else {
        // -------- 5 emitters: step-PAIRS, full 128B-line flushes --------
        const int eid = wv - 1;             // 0..4
        float* __restrict__ stg = &stag[eid][0];
        const int r8 = lane >> 3;           // row within 8-row group
        const int q  = lane & 7;            // 16B column chunk (8 per 32 cols)
        float* __restrict__ outblk = out + (size_t)(grp * 64) * LEN_EPISODE;
        const int colhalf = half << 10;     // column offset: half*1024

        float va[32];

        for (int pr = eid; pr < 32; pr += 5) {
            const int k = pr << 1;          // first local step of the pair
            // need local states k, k+1, k+2
            while (__hip_atomic_load(&cnt, __ATOMIC_ACQUIRE,
                                     __HIP_MEMORY_SCOPE_WORKGROUP) < k + 3) {
                __builtin_amdgcn_s_sleep(2);
            }
            const float2 s0 = ring[k][lane];
            const float2 s1 = ring[k + 1][lane];
            const float2 s2 = ring[k + 2][lane];

            const int gk = k + (half << 6); // global step index
            va[0] = (gk == 0) ? ic.x : twopi * s0.x;    // previous endpoint
            {   // first half: step gk (states s0 -> s1)
                const float U = s0.x, V = s0.y, Un = s1.x, Vn = s1.y;
                EMIT15(va + 1);
            }
            va[16] = twopi * s1.x;                      // endpoint of step gk
            {   // second half: step gk+1 (states s1 -> s2)
                const float U = s1.x, V = s1.y, Un = s2.x, Vn = s2.y;
                EMIT15(va + 17);
            }

#pragma unroll
            for (int j = 0; j < 32; ++j)
                stg[j * 65 + lane] = va[j];

            const int colb = colhalf + (k << 4);  // 32 contiguous columns
#pragma unroll
            for (int rb = 0; rb < 8; ++rb) {
                const int row = (rb << 3) + r8;
                float4 v;
                v.x = stg[(4 * q + 0) * 65 + row];
                v.y = stg[(4 * q + 1) * 65 + row];
                v.z = stg[(4 * q + 2) * 65 + row];
                v.w = stg[(4 * q + 3) * 65 + row];
                *reinterpret_cast<float4*>(outblk + (size_t)row * LEN_EPISODE + colb + 4 * q) = v;
            }
        }
    }
    // final endpoint (output index 2048) intentionally discarded
}

extern "C" void kernel_launch(void* const* d_in, const int* in_sizes, int n_in,
                              void* d_out, int out_size, void* d_ws, size_t ws_size,
                              hipStream_t stream) {
    const float* init   = (const float*)d_in[0];
    const float* params = (const float*)d_in[1];
    float* out = (float*)d_out;
    const int B = in_sizes[0] / 2;  // 16384

    const int block = 384;              // producer + 5 emitters
    const int grid  = 512;              // 2 blocks/CU: timeline halves
    pend_kernel<<<grid, block, 0, stream>>>(init, params, out, B);
}

// Round 32
// 33.916 us; speedup vs baseline: 1.0512x; 1.0512x over previous
//
#include <hip/hip_runtime.h>

#define LEN_EPISODE 2048
#define TW 6.283185307179586
#define HH 0.16

// R32 = R31 with the compile fix: __builtin_nontemporal_store requires a
// native vector type, not HIP_vector_type<float,4>. Use ext_vector_type(4).
// Experiment unchanged: NT stores on the output flush test the L2
// write-allocate theory of the 27.5us plateau (134MB never-read stream
// thrashing 4MB/XCD L2 with dirty writebacks). Everything else byte-identical
// to R28 (best, 27.46us) => absmax must be exactly 0.875.

typedef float f32x4 __attribute__((ext_vector_type(4)));

#define STEPP() do {                                                        \
    const float f1 = Atil * rcf;                                            \
    const float f2 = __builtin_fmaf(nA2s, rsf, A2c * rcf);                  \
    const float f3 = __builtin_fmaf(nA3s, rsf, A3c * rcf);                  \
    rcn = __builtin_fmaf(nsdf, rsf, rcf * cdf);                             \
    rsn = __builtin_fmaf(sdf, rcf, rsf * cdf);                              \
    const float f4 = Atil * rcn;                                            \
    const float s1  = __builtin_amdgcn_sinf(U);                             \
    const float U2  = __builtin_fmaf(c13, V, U);                            \
    const float s2  = __builtin_amdgcn_sinf(U2);                            \
    const float Ub3 = __builtin_fmaf(c23, V, U);                            \
    const float s3a = __builtin_amdgcn_sinf(Ub3);                           \
    const float c3a = __builtin_amdgcn_cosf(Ub3);                           \
    const float Ub4 = __builtin_fmaf(hh, V, U);                             \
    const float s4a = __builtin_amdgcn_sinf(Ub4);                           \
    const float c4a = __builtin_amdgcn_cosf(Ub4);                           \
    const float k1w = __builtin_fmaf(nw2t, s1, __builtin_fmaf(ngam, V, f1)); \
    const float V2  = __builtin_fmaf(c13, k1w, V);                          \
    const float k2w = __builtin_fmaf(nw2t, s2, __builtin_fmaf(ngam, V2, f2)); \
    const float e3  = tph23 * k1w;                                          \
    const float s3  = __builtin_fmaf(e3, c3a,                               \
                      __builtin_fmaf(-0.5f * e3 * e3, s3a, s3a));           \
    const float V3  = __builtin_fmaf(hh, k2w, __builtin_fmaf(nc13, k1w, V)); \
    const float k3w = __builtin_fmaf(nw2t, s3, __builtin_fmaf(ngam, V3, f3)); \
    const float e4  = __builtin_fmaf(tph2, k2w, n23tph2 * k1w);             \
    const float s4  = __builtin_fmaf(e4, c4a,                               \
                      __builtin_fmaf(-0.5f * e4 * e4, s4a, s4a));           \
    const float V4  = __builtin_fmaf(hh, (k1w - k2w) + k3w, V);             \
    const float k4w = __builtin_fmaf(nw2t, s4, __builtin_fmaf(ngam, V4, f4)); \
    Un = __builtin_fmaf(h8, __builtin_fmaf(3.0f, V2 + V3, V) + V4, U);      \
    Vn = __builtin_fmaf(h8, __builtin_fmaf(3.0f, k2w + k3w, k1w) + k4w, V); \
} while (0)

// Cubic Hermite basis (compile-time doubles), radians+h folded in.
#define B00(t) ((1.0-(t))*(1.0-(t))*(1.0+2.0*(t)))
#define B10(t) ((t)*(1.0-(t))*(1.0-(t)))
#define B01(t) ((t)*(t)*(3.0-2.0*(t)))
#define B11(t) ((t)*(t)*((t)-1.0))
#define HERMT(t)                                                              \
    __builtin_fmaf((float)(TW * B00(t)), U,                                   \
    __builtin_fmaf((float)(TW * B10(t) * HH), V,                              \
    __builtin_fmaf((float)(TW * B01(t)), Un, (float)(TW * B11(t) * HH) * Vn)))

#define EMIT15(dst) do {                                                      \
    (dst)[0]  = HERMT( 1.0/16.0); (dst)[1]  = HERMT( 2.0/16.0);               \
    (dst)[2]  = HERMT( 3.0/16.0); (dst)[3]  = HERMT( 4.0/16.0);               \
    (dst)[4]  = HERMT( 5.0/16.0); (dst)[5]  = HERMT( 6.0/16.0);               \
    (dst)[6]  = HERMT( 7.0/16.0); (dst)[7]  = HERMT( 8.0/16.0);               \
    (dst)[8]  = HERMT( 9.0/16.0); (dst)[9]  = HERMT(10.0/16.0);               \
    (dst)[10] = HERMT(11.0/16.0); (dst)[11] = HERMT(12.0/16.0);               \
    (dst)[12] = HERMT(13.0/16.0); (dst)[13] = HERMT(14.0/16.0);               \
    (dst)[14] = HERMT(15.0/16.0);                                             \
} while (0)

#define COMMIT() do { U = Un; V = Vn; rcf = rcn; rsf = rsn; } while (0)

__global__ __launch_bounds__(512) void pend_kernel(
    const float* __restrict__ init,    // (B, 2)
    const float* __restrict__ params,  // (B, 4)
    float* __restrict__ out,           // (B, LEN_EPISODE)
    int B)
{
    __shared__ float2 ring[129][64];   // [state k][lane] -- written ONCE each
    __shared__ float  stag[7][32 * 65];// per-emitter transpose staging (pairs)
    __shared__ int    cnt;             // number of published states

    const int tid  = threadIdx.x;
    const int lane = tid & 63;
    const int wv   = tid >> 6;          // 0 = producer; 1..7 = emitters
    const int b = blockIdx.x * 64 + lane;

    const float twopi  = 6.283185307179586f;
    const float inv2pi = 0.15915494309189535f;

    const float2 ic = *reinterpret_cast<const float2*>(init + 2 * b);

    if (tid == 0) cnt = 0;
    __syncthreads();                    // cnt initialized before anyone spins

    if (wv == 0) {
        // ---------------- producer: pure integration ----------------
        const float4 p  = *reinterpret_cast<const float4*>(params + 4 * b);
        const float omega = p.x, gamma = p.y, A = p.z, phi = p.w;

        float U = ic.x * inv2pi;
        float V = ic.y * inv2pi;

        const float hh    = 0.16f;
        const float c13   = (float)(0.16 / 3.0);
        const float c23   = (float)(0.32 / 3.0);
        const float nc13  = -c13;
        const float h8    = 0.02f;
        const float tph23 = (float)(TW * 0.16 * 0.16 / 3.0);   // 2pi h^2/3
        const float tph2  = (float)(TW * 0.16 * 0.16);         // 2pi h^2
        const float n23tph2 = (float)(-TW * 2.0 * 0.16 * 0.16 / 3.0);
        const float ngam  = -gamma;
        const float nw2t  = -(omega * omega) * inv2pi;
        const float Atil  = A * omega * omega * inv2pi;

        const double c_d = 6.283185307179586476925287 * (double)phi;
        const float cdf  = (float)::cos(c_d * 0.16);
        const float sdf  = (float)::sin(c_d * 0.16);
        const float nsdf = -sdf;
        const float A2c  = Atil * (float)::cos(c_d * (0.16 / 3.0));
        const float nA2s = -Atil * (float)::sin(c_d * (0.16 / 3.0));
        const float A3c  = Atil * (float)::cos(c_d * (0.32 / 3.0));
        const float nA3s = -Atil * (float)::sin(c_d * (0.32 / 3.0));

        float rcf = 1.0f, rsf = 0.0f;
        float Un, Vn, rcn, rsn;

        for (int k4 = 0; k4 < 128; k4 += 4) {
#pragma unroll
            for (int j = 0; j < 4; ++j) {
                ring[k4 + j][lane] = make_float2(U, V);
                STEPP(); COMMIT();
            }
            // RELEASE orders the 4 ring writes above.
            if (lane == 0)
                __hip_atomic_store(&cnt, k4 + 4, __ATOMIC_RELEASE,
                                   __HIP_MEMORY_SCOPE_WORKGROUP);
        }
        ring[128][lane] = make_float2(U, V);            // final endpoint state
        if (lane == 0)
            __hip_atomic_store(&cnt, 129, __ATOMIC_RELEASE,
                               __HIP_MEMORY_SCOPE_WORKGROUP);
    } else {
        // -------- 7 emitters: step-PAIRS, 128B-line NT flushes --------
        const int eid = wv - 1;             // 0..6
        float* __restrict__ stg = &stag[eid][0];
        const int r8 = lane >> 3;           // row within 8-row group
        const int q  = lane & 7;            // 16B column chunk (8 per 32 cols)
        float* __restrict__ outblk = out + (size_t)(blockIdx.x * 64) * LEN_EPISODE;

        float va[32];

        for (int pr = eid; pr < 64; pr += 7) {
            const int k = pr << 1;          // first step of the pair
            // need states k, k+1, k+2
            while (__hip_atomic_load(&cnt, __ATOMIC_ACQUIRE,
                                     __HIP_MEMORY_SCOPE_WORKGROUP) < k + 3) {
                __builtin_amdgcn_s_sleep(2);
            }
            const float2 s0 = ring[k][lane];
            const float2 s1 = ring[k + 1][lane];
            const float2 s2 = ring[k + 2][lane];

            va[0] = (k == 0) ? ic.x : twopi * s0.x;     // previous endpoint
            {   // first half: step k (states s0 -> s1)
                const float U = s0.x, V = s0.y, Un = s1.x, Vn = s1.y;
                EMIT15(va + 1);
            }
            va[16] = twopi * s1.x;                      // endpoint of step k
            {   // second half: step k+1 (states s1 -> s2)
                const float U = s1.x, V = s1.y, Un = s2.x, Vn = s2.y;
                EMIT15(va + 17);
            }

#pragma unroll
            for (int j = 0; j < 32; ++j)
                stg[j * 65 + lane] = va[j];

            const int colb = k << 4;        // 32 contiguous output columns
#pragma unroll
            for (int rb = 0; rb < 8; ++rb) {
                const int row = (rb << 3) + r8;
                f32x4 v;
                v.x = stg[(4 * q + 0) * 65 + row];
                v.y = stg[(4 * q + 1) * 65 + row];
                v.z = stg[(4 * q + 2) * 65 + row];
                v.w = stg[(4 * q + 3) * 65 + row];
                __builtin_nontemporal_store(
                    v, reinterpret_cast<f32x4*>(
                           outblk + (size_t)row * LEN_EPISODE + colb + 4 * q));
            }
        }
    }
    // final endpoint (output index 2048) intentionally discarded
}

extern "C" void kernel_launch(void* const* d_in, const int* in_sizes, int n_in,
                              void* d_out, int out_size, void* d_ws, size_t ws_size,
                              hipStream_t stream) {
    const float* init   = (const float*)d_in[0];
    const float* params = (const float*)d_in[1];
    float* out = (float*)d_out;
    const int B = in_sizes[0] / 2;  // 16384

    const int block = 512;              // wave 0 producer, 7 emitter waves
    const int grid  = B / 64;           // 256 blocks, exact cover
    pend_kernel<<<grid, block, 0, stream>>>(init, params, out, B);
}

// Round 33
// 27.461 us; speedup vs baseline: 1.2983x; 1.2350x over previous
//
#include <hip/hip_runtime.h>

#define LEN_EPISODE 2048
#define TW 6.283185307179586
#define HH 0.16

// R33 = R28 exactly (best measured: 27.46us, absmax 0.875). Final revert
// after the plateau-probe ledger completed: producer speed x3 flat; 7th
// emitter flat; 256B segments worse; 2 blocks/CU worse; NT stores worse.
// Structure: wave 0 producer (RK4-3/8 h=0.16, one-sin critical path via
// k-free linearized s3/s4), no-wraparound ring[129], 7 pair-emitters
// (15 Hermite interiors + endpoint per step, LDS transpose, 128B-line
// coalesced flushes). ~52x over the round-1 baseline.

#define STEPP() do {                                                        \
    const float f1 = Atil * rcf;                                            \
    const float f2 = __builtin_fmaf(nA2s, rsf, A2c * rcf);                  \
    const float f3 = __builtin_fmaf(nA3s, rsf, A3c * rcf);                  \
    rcn = __builtin_fmaf(nsdf, rsf, rcf * cdf);                             \
    rsn = __builtin_fmaf(sdf, rcf, rsf * cdf);                              \
    const float f4 = Atil * rcn;                                            \
    const float s1  = __builtin_amdgcn_sinf(U);                             \
    const float U2  = __builtin_fmaf(c13, V, U);                            \
    const float s2  = __builtin_amdgcn_sinf(U2);                            \
    const float Ub3 = __builtin_fmaf(c23, V, U);                            \
    const float s3a = __builtin_amdgcn_sinf(Ub3);                           \
    const float c3a = __builtin_amdgcn_cosf(Ub3);                           \
    const float Ub4 = __builtin_fmaf(hh, V, U);                             \
    const float s4a = __builtin_amdgcn_sinf(Ub4);                           \
    const float c4a = __builtin_amdgcn_cosf(Ub4);                           \
    const float k1w = __builtin_fmaf(nw2t, s1, __builtin_fmaf(ngam, V, f1)); \
    const float V2  = __builtin_fmaf(c13, k1w, V);                          \
    const float k2w = __builtin_fmaf(nw2t, s2, __builtin_fmaf(ngam, V2, f2)); \
    const float e3  = tph23 * k1w;                                          \
    const float s3  = __builtin_fmaf(e3, c3a,                               \
                      __builtin_fmaf(-0.5f * e3 * e3, s3a, s3a));           \
    const float V3  = __builtin_fmaf(hh, k2w, __builtin_fmaf(nc13, k1w, V)); \
    const float k3w = __builtin_fmaf(nw2t, s3, __builtin_fmaf(ngam, V3, f3)); \
    const float e4  = __builtin_fmaf(tph2, k2w, n23tph2 * k1w);             \
    const float s4  = __builtin_fmaf(e4, c4a,                               \
                      __builtin_fmaf(-0.5f * e4 * e4, s4a, s4a));           \
    const float V4  = __builtin_fmaf(hh, (k1w - k2w) + k3w, V);             \
    const float k4w = __builtin_fmaf(nw2t, s4, __builtin_fmaf(ngam, V4, f4)); \
    Un = __builtin_fmaf(h8, __builtin_fmaf(3.0f, V2 + V3, V) + V4, U);      \
    Vn = __builtin_fmaf(h8, __builtin_fmaf(3.0f, k2w + k3w, k1w) + k4w, V); \
} while (0)

// Cubic Hermite basis (compile-time doubles), radians+h folded in.
#define B00(t) ((1.0-(t))*(1.0-(t))*(1.0+2.0*(t)))
#define B10(t) ((t)*(1.0-(t))*(1.0-(t)))
#define B01(t) ((t)*(t)*(3.0-2.0*(t)))
#define B11(t) ((t)*(t)*((t)-1.0))
#define HERMT(t)                                                              \
    __builtin_fmaf((float)(TW * B00(t)), U,                                   \
    __builtin_fmaf((float)(TW * B10(t) * HH), V,                              \
    __builtin_fmaf((float)(TW * B01(t)), Un, (float)(TW * B11(t) * HH) * Vn)))

#define EMIT15(dst) do {                                                      \
    (dst)[0]  = HERMT( 1.0/16.0); (dst)[1]  = HERMT( 2.0/16.0);               \
    (dst)[2]  = HERMT( 3.0/16.0); (dst)[3]  = HERMT( 4.0/16.0);               \
    (dst)[4]  = HERMT( 5.0/16.0); (dst)[5]  = HERMT( 6.0/16.0);               \
    (dst)[6]  = HERMT( 7.0/16.0); (dst)[7]  = HERMT( 8.0/16.0);               \
    (dst)[8]  = HERMT( 9.0/16.0); (dst)[9]  = HERMT(10.0/16.0);               \
    (dst)[10] = HERMT(11.0/16.0); (dst)[11] = HERMT(12.0/16.0);               \
    (dst)[12] = HERMT(13.0/16.0); (dst)[13] = HERMT(14.0/16.0);               \
    (dst)[14] = HERMT(15.0/16.0);                                             \
} while (0)

#define COMMIT() do { U = Un; V = Vn; rcf = rcn; rsf = rsn; } while (0)

__global__ __launch_bounds__(512) void pend_kernel(
    const float* __restrict__ init,    // (B, 2)
    const float* __restrict__ params,  // (B, 4)
    float* __restrict__ out,           // (B, LEN_EPISODE)
    int B)
{
    __shared__ float2 ring[129][64];   // [state k][lane] -- written ONCE each
    __shared__ float  stag[7][32 * 65];// per-emitter transpose staging (pairs)
    __shared__ int    cnt;             // number of published states

    const int tid  = threadIdx.x;
    const int lane = tid & 63;
    const int wv   = tid >> 6;          // 0 = producer; 1..7 = emitters
    const int b = blockIdx.x * 64 + lane;

    const float twopi  = 6.283185307179586f;
    const float inv2pi = 0.15915494309189535f;

    const float2 ic = *reinterpret_cast<const float2*>(init + 2 * b);

    if (tid == 0) cnt = 0;
    __syncthreads();                    // cnt initialized before anyone spins

    if (wv == 0) {
        // ---------------- producer: pure integration ----------------
        const float4 p  = *reinterpret_cast<const float4*>(params + 4 * b);
        const float omega = p.x, gamma = p.y, A = p.z, phi = p.w;

        float U = ic.x * inv2pi;
        float V = ic.y * inv2pi;

        const float hh    = 0.16f;
        const float c13   = (float)(0.16 / 3.0);
        const float c23   = (float)(0.32 / 3.0);
        const float nc13  = -c13;
        const float h8    = 0.02f;
        const float tph23 = (float)(TW * 0.16 * 0.16 / 3.0);   // 2pi h^2/3
        const float tph2  = (float)(TW * 0.16 * 0.16);         // 2pi h^2
        const float n23tph2 = (float)(-TW * 2.0 * 0.16 * 0.16 / 3.0);
        const float ngam  = -gamma;
        const float nw2t  = -(omega * omega) * inv2pi;
        const float Atil  = A * omega * omega * inv2pi;

        const double c_d = 6.283185307179586476925287 * (double)phi;
        const float cdf  = (float)::cos(c_d * 0.16);
        const float sdf  = (float)::sin(c_d * 0.16);
        const float nsdf = -sdf;
        const float A2c  = Atil * (float)::cos(c_d * (0.16 / 3.0));
        const float nA2s = -Atil * (float)::sin(c_d * (0.16 / 3.0));
        const float A3c  = Atil * (float)::cos(c_d * (0.32 / 3.0));
        const float nA3s = -Atil * (float)::sin(c_d * (0.32 / 3.0));

        float rcf = 1.0f, rsf = 0.0f;
        float Un, Vn, rcn, rsn;

        for (int k4 = 0; k4 < 128; k4 += 4) {
#pragma unroll
            for (int j = 0; j < 4; ++j) {
                ring[k4 + j][lane] = make_float2(U, V);
                STEPP(); COMMIT();
            }
            // RELEASE orders the 4 ring writes above.
            if (lane == 0)
                __hip_atomic_store(&cnt, k4 + 4, __ATOMIC_RELEASE,
                                   __HIP_MEMORY_SCOPE_WORKGROUP);
        }
        ring[128][lane] = make_float2(U, V);            // final endpoint state
        if (lane == 0)
            __hip_atomic_store(&cnt, 129, __ATOMIC_RELEASE,
                               __HIP_MEMORY_SCOPE_WORKGROUP);
    } else {
        // -------- 7 emitters: step-PAIRS, full 128B-line flushes --------
        const int eid = wv - 1;             // 0..6
        float* __restrict__ stg = &stag[eid][0];
        const int r8 = lane >> 3;           // row within 8-row group
        const int q  = lane & 7;            // 16B column chunk (8 per 32 cols)
        float* __restrict__ outblk = out + (size_t)(blockIdx.x * 64) * LEN_EPISODE;

        float va[32];

        for (int pr = eid; pr < 64; pr += 7) {
            const int k = pr << 1;          // first step of the pair
            // need states k, k+1, k+2
            while (__hip_atomic_load(&cnt, __ATOMIC_ACQUIRE,
                                     __HIP_MEMORY_SCOPE_WORKGROUP) < k + 3) {
                __builtin_amdgcn_s_sleep(2);
            }
            const float2 s0 = ring[k][lane];
            const float2 s1 = ring[k + 1][lane];
            const float2 s2 = ring[k + 2][lane];

            va[0] = (k == 0) ? ic.x : twopi * s0.x;     // previous endpoint
            {   // first half: step k (states s0 -> s1)
                const float U = s0.x, V = s0.y, Un = s1.x, Vn = s1.y;
                EMIT15(va + 1);
            }
            va[16] = twopi * s1.x;                      // endpoint of step k
            {   // second half: step k+1 (states s1 -> s2)
                const float U = s1.x, V = s1.y, Un = s2.x, Vn = s2.y;
                EMIT15(va + 17);
            }

#pragma unroll
            for (int j = 0; j < 32; ++j)
                stg[j * 65 + lane] = va[j];

            const int colb = k << 4;        // 32 contiguous output columns
#pragma unroll
            for (int rb = 0; rb < 8; ++rb) {
                const int row = (rb << 3) + r8;
                float4 v;
                v.x = stg[(4 * q + 0) * 65 + row];
                v.y = stg[(4 * q + 1) * 65 + row];
                v.z = stg[(4 * q + 2) * 65 + row];
                v.w = stg[(4 * q + 3) * 65 + row];
                *reinterpret_cast<float4*>(outblk + (size_t)row * LEN_EPISODE + colb + 4 * q) = v;
            }
        }
    }
    // final endpoint (output index 2048) intentionally discarded
}

extern "C" void kernel_launch(void* const* d_in, const int* in_sizes, int n_in,
                              void* d_out, int out_size, void* d_ws, size_t ws_size,
                              hipStream_t stream) {
    const float* init   = (const float*)d_in[0];
    const float* params = (const float*)d_in[1];
    float* out = (float*)d_out;
    const int B = in_sizes[0] / 2;  // 16384

    const int block = 512;              // wave 0 producer, 7 emitter waves
    const int grid  = B / 64;           // 256 blocks, exact cover
    pend_kernel<<<grid, block, 0, stream>>>(init, params, out, B);
}